// Round 1
// baseline (94.968 us; speedup 1.0000x reference)
//
#include <hip/hip_runtime.h>

// Output[k*64 + c] = Input[s*64 + c], where
//   k in [0, 720*1280), x = k % 720, y = k / 720, s = x*1280 + y.
// Pure 256-byte-block transpose of a 720x1280 grid. Memory-bound.

#define HH 720
#define WW 1280
#define CC 64
#define V4 (CC / 4)          // 16 float4 per pixel
#define TOTAL4 (HH * WW * V4) // 14,745,600 float4 elements

__global__ __launch_bounds__(256) void vtl_gather_kernel(
    const float4* __restrict__ in, float4* __restrict__ out) {
    int idx = blockIdx.x * blockDim.x + threadIdx.x;   // float4 index, < 2^31
    if (idx >= TOTAL4) return;
    int k = idx >> 4;        // output pixel index
    int j = idx & 15;        // float4 slot within the 64-channel vector
    int x = k % HH;          // source row   (compiler emits magic-mul for /720)
    int y = k / HH;          // source col
    int s = x * WW + y;      // source pixel index
    out[idx] = in[s * V4 + j];
}

extern "C" void kernel_launch(void* const* d_in, const int* in_sizes, int n_in,
                              void* d_out, int out_size, void* d_ws, size_t ws_size,
                              hipStream_t stream) {
    const float4* in = (const float4*)d_in[0];  // feature_map, float32 [1,720,1280,64]
    float4* out = (float4*)d_out;               // float32 [1,720,1280,64]
    // d_in[1] (matrix) is ignored: reference overwrites it with identity.
    constexpr int threads = 256;
    constexpr int blocks = TOTAL4 / threads;    // 57,600 exactly (no remainder)
    vtl_gather_kernel<<<blocks, threads, 0, stream>>>(in, out);
}

// Round 2
// 94.361 us; speedup vs baseline: 1.0064x; 1.0064x over previous
//
#include <hip/hip_runtime.h>

// out[k] = in[s], k = q*720 + r, s = r*1280 + q  (r in [0,720), q in [0,1280))
// => 256-byte-block transpose of a 720x1280 pixel grid (64 f32 channels/pixel).
// LDS-tiled so both global reads and writes are 4KB-contiguous runs.

#define HH 720      // r extent (source rows)
#define WW 1280     // q extent (source cols)
#define TX 16       // tile extent in r
#define TY 16       // tile extent in q
#define NTX (HH / TX)   // 45
#define NTY (WW / TY)   // 80
// one pixel = 64 f32 = 16 float4 = 256 B; tile = 256 pixels = 64 KB

__global__ __launch_bounds__(256) void vtl_tile_kernel(
    const float* __restrict__ in, float4* __restrict__ out) {
  __shared__ float4 lds[TX * TY * 16];  // layout: x*256 + y*16 + j  (source order)

  const int tile = blockIdx.x;
  const int tx = tile % NTX;
  const int ty = tile / NTX;
  const int x0 = tx * TX;   // source row base
  const int y0 = ty * TY;   // source col base
  const int wave = threadIdx.x >> 6;
  const int lane = threadIdx.x & 63;

  // ---- load phase: 16 source rows, each 4KB contiguous -> LDS (linear) ----
  // wave handles rows x = wave*4 .. wave*4+3; each row = 4 chunks of 64 float4.
  for (int r = 0; r < 4; ++r) {
    const int xr = wave * 4 + r;
    const float* grow = in + ((size_t)(x0 + xr) * WW + y0) * 64;  // float units
    float4* lbase = &lds[xr * 256];
    for (int c = 0; c < 4; ++c) {
      __builtin_amdgcn_global_load_lds(
          (const __attribute__((address_space(1))) void*)(grow + (size_t)(c * 64 + lane) * 4),
          (__attribute__((address_space(3))) void*)(lbase + c * 64),
          16, 0, 0);
    }
  }
  __syncthreads();  // compiler emits vmcnt(0) drain before s_barrier

  // ---- store phase: 16 output rows (fixed q), each 4KB contiguous ----
  // wave handles y = wave*4 .. wave*4+3; chunk c covers pixels x = c*4..c*4+3.
  for (int r = 0; r < 4; ++r) {
    const int yr = wave * 4 + r;
    float4* gout = out + ((size_t)(y0 + yr) * HH + x0) * 16;
    for (int c = 0; c < 4; ++c) {
      const int x = c * 4 + (lane >> 4);
      gout[c * 64 + lane] = lds[x * 256 + yr * 16 + (lane & 15)];
    }
  }
}

extern "C" void kernel_launch(void* const* d_in, const int* in_sizes, int n_in,
                              void* d_out, int out_size, void* d_ws, size_t ws_size,
                              hipStream_t stream) {
  const float* in = (const float*)d_in[0];  // feature_map [1,720,1280,64] f32
  float4* out = (float4*)d_out;             // [1,720,1280,64] f32
  constexpr int blocks = NTX * NTY;         // 3600 tiles, exact fit
  vtl_tile_kernel<<<blocks, 256, 0, stream>>>(in, out);
}

// Round 3
// 94.008 us; speedup vs baseline: 1.0102x; 1.0038x over previous
//
#include <hip/hip_runtime.h>

// out[k] = in[s], k = q*720 + r, s = r*1280 + q  (r in [0,720), q in [0,1280))
// 256-byte-block transpose of a 720x1280 pixel grid (64 f32 channels/pixel).
// Tile = 8 source rows x 16 source cols of pixels = 32 KB LDS
//   -> 5 blocks/CU resident (20 waves/CU) so load/store phases of different
//      blocks overlap (round-2 64KB tile = 2 blocks/CU was phase-serialized).
// Reads: 4KB contiguous runs; writes: 2KB contiguous runs.

#define HH 720
#define WW 1280
#define TR 8                 // tile rows (r / source-row extent)
#define TQ 16                // tile cols (q / source-col extent)
#define NTX (HH / TR)        // 90
#define NTY (WW / TQ)        // 80

__global__ __launch_bounds__(256) void vtl_tile_kernel(
    const float* __restrict__ in, float4* __restrict__ out) {
  __shared__ float4 lds[TR * TQ * 16];  // 32 KB, layout: x*256 + y*16 + j (source order)

  const int tile = blockIdx.x;
  const int ty = tile % NTY;           // fast: consecutive blocks read adjacent
  const int tx = tile / NTY;           //       4KB chunks of the same source rows
  const int x0 = tx * TR;
  const int y0 = ty * TQ;
  const int wave = threadIdx.x >> 6;
  const int lane = threadIdx.x & 63;

  // ---- load: 8 source rows, each 4KB contiguous -> LDS (linear) ----
  // wave handles rows x = 2*wave, 2*wave+1; each row = 4 chunks of 64 float4.
  for (int r = 0; r < 2; ++r) {
    const int xr = wave * 2 + r;
    const float* grow = in + ((size_t)(x0 + xr) * WW + y0) * 64;
    float4* lbase = &lds[xr * 256];
    for (int c = 0; c < 4; ++c) {
      __builtin_amdgcn_global_load_lds(
          (const __attribute__((address_space(1))) void*)(grow + (size_t)(c * 64 + lane) * 4),
          (__attribute__((address_space(3))) void*)(lbase + c * 64),
          16, 0, 0);
    }
  }
  __syncthreads();

  // ---- store: 16 output runs (fixed q), each 2KB contiguous ----
  // wave handles y = 4*wave .. 4*wave+3; chunk c covers pixels x = c*4..c*4+3.
  for (int r = 0; r < 4; ++r) {
    const int yr = wave * 4 + r;
    float4* gout = out + ((size_t)(y0 + yr) * HH + x0) * 16;
    for (int c = 0; c < 2; ++c) {
      const int x = c * 4 + (lane >> 4);
      gout[c * 64 + lane] = lds[x * 256 + yr * 16 + (lane & 15)];
    }
  }
}

extern "C" void kernel_launch(void* const* d_in, const int* in_sizes, int n_in,
                              void* d_out, int out_size, void* d_ws, size_t ws_size,
                              hipStream_t stream) {
  const float* in = (const float*)d_in[0];  // feature_map [1,720,1280,64] f32
  float4* out = (float4*)d_out;             // [1,720,1280,64] f32
  constexpr int blocks = NTX * NTY;         // 7200 tiles, exact fit
  vtl_tile_kernel<<<blocks, 256, 0, stream>>>(in, out);
}

// Round 5
// 78.981 us; speedup vs baseline: 1.2024x; 1.1903x over previous
//
#include <hip/hip_runtime.h>

// out[k*64+c] = in[s*64+c], k in [0,720*1280), s = (k%720)*1280 + (k/720).
// Pure 256-byte-block transpose, memory-bound, zero reuse.
// Round 5: non-temporal loads+stores (nt bit) to bypass L2/L3 allocation —
// rounds 1-3 showed access pattern and occupancy don't move 5.0 TB/s.
// (Round-4 fix: builtin needs a native clang vector type, not HIP float4.)

#define HH 720
#define WW 1280
#define V4 16                  // 16-byte vectors per pixel
#define TOTAL4 (HH * WW * V4)  // 14,745,600

typedef float f32x4 __attribute__((ext_vector_type(4)));

__global__ __launch_bounds__(256) void vtl_gather_nt_kernel(
    const f32x4* __restrict__ in, f32x4* __restrict__ out) {
  int idx = blockIdx.x * blockDim.x + threadIdx.x;  // 16B-vector index
  int k = idx >> 4;   // output pixel
  int j = idx & 15;   // vector slot within pixel
  int x = k % HH;     // source row
  int y = k / HH;     // source col
  int s = x * WW + y; // source pixel
  f32x4 v = __builtin_nontemporal_load(&in[s * V4 + j]);
  __builtin_nontemporal_store(v, &out[idx]);
}

extern "C" void kernel_launch(void* const* d_in, const int* in_sizes, int n_in,
                              void* d_out, int out_size, void* d_ws, size_t ws_size,
                              hipStream_t stream) {
  const f32x4* in = (const f32x4*)d_in[0];  // feature_map [1,720,1280,64] f32
  f32x4* out = (f32x4*)d_out;
  constexpr int threads = 256;
  constexpr int blocks = TOTAL4 / threads;  // 57,600 exact
  vtl_gather_nt_kernel<<<blocks, threads, 0, stream>>>(in, out);
}